// Round 17
// baseline (6645.419 us; speedup 1.0000x reference)
//
#include <hip/hip_runtime.h>
#include <hip/hip_fp16.h>

#define BB 32
#define LL 512
#define HH 1024
#define NL 4
#define TPL 32   // tiles (blocks) per layer
#define CPB 32   // cols per block
#define TAGM 0x0001000100010001ULL   // LSB of each f16; per-f16 tags -> tear-proof
#define SROW 1032  // LDS row stride (f16)

typedef unsigned long long ull;
typedef _Float16 f16x8 __attribute__((ext_vector_type(8)));
typedef float    f32x4 __attribute__((ext_vector_type(4)));

__device__ __forceinline__ f16x8 cvt8(const float* __restrict__ p) {
  f32x4 lo = *reinterpret_cast<const f32x4*>(p);
  f32x4 hi = *reinterpret_cast<const f32x4*>(p + 4);
  f16x8 r;
#pragma unroll
  for (int e = 0; e < 4; ++e) { r[e] = (_Float16)lo[e]; r[e + 4] = (_Float16)hi[e]; }
  return r;
}

__device__ __forceinline__ ull tag_bad(f16x8 v, ull want) {
  union { f16x8 v; ull u[2]; } c; c.v = v;
  return ((c.u[0] ^ want) | (c.u[1] ^ want)) & TAGM;
}

__device__ __forceinline__ ull check16(const f16x8* __restrict__ a, ull want) {
  ull bad = 0;
#pragma unroll
  for (int it = 0; it < 16; ++it) bad |= tag_bad(a[it], want);
  return bad;
}

// Persistent pipeline, 128 active blocks: layer = blockIdx&7 (XCD-locality
// heuristic only; tags + MALL-atomic retry keep correctness placement-free).
// Hidden recurrence: dual-stored h, tag-settle on local L2 (no flags).
// Input edge: per-thread flag HINT (publish un-drained) + tag-settle net.
__global__ __launch_bounds__(256, 1) void rnn_persist(
    const float* __restrict__ x,   // [B][L][H] f32
    const float* __restrict__ h0,  // [NL][B][H] f32
    const float* __restrict__ WI,  // [NL][H][H] f32
    const float* __restrict__ BI,  // [NL][H]
    const float* __restrict__ WH,  // [NL][H][H] f32
    const float* __restrict__ BH,  // [NL][H]
    float* __restrict__ out,       // [B][L][H] f32 ++ hfinal [NL][B][H]
    _Float16* __restrict__ hbuf,   // [NL][RS][B][H] f16 (tagged)
    unsigned* __restrict__ pflag,  // [NL][TPL]: v => step v-1 stores issued
    int rsmask, int rshift) {
  const int l = blockIdx.x & 7;
  if (l >= NL) return;
  const int tile = blockIdx.x >> 3;
  const int c0   = tile * CPB;
  const int tid  = threadIdx.x;
  const int w    = tid >> 6;          // wave -> k-quarter
  const int lane = tid & 63;
  const int crow = lane & 15;
  const int kgrp = lane >> 4;

  extern __shared__ char smem[];
  _Float16* sIn  = (_Float16*)smem;                     // [32][SROW]
  _Float16* sHid = sIn + 32 * SROW;                     // [32][SROW]
  float*    redp = (float*)(sHid + 32 * SROW);          // [4][2][16][34]
#define RED(W, RT, R, C) redp[((((W)*2 + (RT)) * 16 + (R)) * 34) + (C)]

  // ---- weight fragments -> registers (once): both matrices, own k-quarter ----
  f16x8 wIf[2][8], wHf[2][8];
  {
    const float* WIb = WI + (size_t)l * HH * HH;
    const float* WHb = WH + (size_t)l * HH * HH;
#pragma unroll
    for (int ct = 0; ct < 2; ++ct) {
      const size_t row = (size_t)(c0 + ct * 16 + crow) * HH;
#pragma unroll
      for (int j = 0; j < 8; ++j) {
        const int k = w * 256 + kgrp * 8 + j * 32;
        wIf[ct][j] = cvt8(WIb + row + k);
        wHf[ct][j] = cvt8(WHb + row + k);
      }
    }
  }

  // staging geometry: q = it*256+tid -> row=q>>7, col=(q&127)*8. Since
  // 256 ≡ 0 (mod 128), a thread's 16 quanta all share col=(tid&127)*8 ->
  // they lie in ONE producer tile: ptile = (tid&127)>>2. Per-thread gating.
  const int ptile = (tid & 127) >> 2;

  const int rb2 = tid >> 2;
  const int c8  = (tid & 3) * 8;
  float bias8[8];
#pragma unroll
  for (int j = 0; j < 8; ++j)
    bias8[j] = BI[l * HH + c0 + c8 + j] + BH[l * HH + c0 + c8 + j];

  for (int t = 0; t < LL; ++t) {
    const ull wantI = (((t >> rshift) & 1) ^ 1) ? TAGM : 0ULL;        // gen t
    const ull wantH = ((((t - 1) >> rshift) & 1) ^ 1) ? TAGM : 0ULL;  // gen t-1

    // ---------- per-thread self-gates (no barrier needed) ----------
    if (l > 0) {   // input hint: my producer tile has issued step-t stores
      while (__hip_atomic_load(&pflag[(l - 1) * TPL + ptile], __ATOMIC_RELAXED,
                               __HIP_MEMORY_SCOPE_AGENT) < (unsigned)(t + 1))
        __builtin_amdgcn_s_sleep(1);
    }
    if (l < NL - 1 && t > rsmask) {   // WAR (only if ring actually reuses)
      while (__hip_atomic_load(&pflag[(l + 1) * TPL + ptile], __ATOMIC_RELAXED,
                               __HIP_MEMORY_SCOPE_AGENT) < (unsigned)(t - rsmask))
        __builtin_amdgcn_s_sleep(1);
    }

    // ---------- BATCHED coalesced staging (one exposure) ----------
    f16x8 tin[16], thid[16];
    const _Float16* srcI =
        hbuf + ((size_t)(l - 1) * (rsmask + 1) + (t & rsmask)) * BB * HH;
    const _Float16* srcH =
        hbuf + ((size_t)l * (rsmask + 1) + ((t - 1) & rsmask)) * BB * HH;

    if (l == 0) {
#pragma unroll
      for (int it = 0; it < 16; ++it) {
        const int q = it * 256 + tid, row = q >> 7, col = (q & 127) * 8;
        tin[it] = cvt8(x + ((size_t)row * LL + t) * HH + col);
      }
    } else {
#pragma unroll
      for (int it = 0; it < 16; ++it) {
        const int q = it * 256 + tid, row = q >> 7, col = (q & 127) * 8;
        tin[it] = *reinterpret_cast<const f16x8*>(srcI + (size_t)row * HH + col);
      }
    }
    if (t == 0) {
#pragma unroll
      for (int it = 0; it < 16; ++it) {
        const int q = it * 256 + tid, row = q >> 7, col = (q & 127) * 8;
        thid[it] = cvt8(h0 + ((size_t)l * BB + row) * HH + col);
      }
    } else {
#pragma unroll
      for (int it = 0; it < 16; ++it) {
        const int q = it * 256 + tid, row = q >> 7, col = (q & 127) * 8;
        thid[it] = *reinterpret_cast<const f16x8*>(srcH + (size_t)row * HH + col);
      }
    }

    // ---------- settle: tiered batched-conditional retry rounds ----------
    // hidden (same-XCD): volatile rounds (L2-fresh, producer updates in place),
    // cap 4, then MALL-atomic rounds. input (cross-XCD): straight to atomic
    // rounds (consumer L2 may hold a permanently-stale line -> skip volatile).
    if (t != 0) {
      int rounds = 0;
      while (check16(thid, wantH)) {
        if (rounds++ < 4) {
#pragma unroll
          for (int it = 0; it < 16; ++it) {
            if (tag_bad(thid[it], wantH)) {
              const int q = it * 256 + tid, row = q >> 7, col = (q & 127) * 8;
              const volatile ull* vp =
                  reinterpret_cast<const volatile ull*>(srcH + (size_t)row * HH + col);
              ull lo = vp[0], hi = vp[1];
              union { ull u[2]; f16x8 v; } c; c.u[0] = lo; c.u[1] = hi;
              thid[it] = c.v;
            }
          }
        } else {
#pragma unroll
          for (int it = 0; it < 16; ++it) {
            if (tag_bad(thid[it], wantH)) {
              const int q = it * 256 + tid, row = q >> 7, col = (q & 127) * 8;
              const ull* p = reinterpret_cast<const ull*>(srcH + (size_t)row * HH + col);
              ull lo = __hip_atomic_load(p,     __ATOMIC_RELAXED, __HIP_MEMORY_SCOPE_AGENT);
              ull hi = __hip_atomic_load(p + 1, __ATOMIC_RELAXED, __HIP_MEMORY_SCOPE_AGENT);
              union { ull u[2]; f16x8 v; } c; c.u[0] = lo; c.u[1] = hi;
              thid[it] = c.v;
            }
          }
        }
      }
    }
    if (l != 0) {
      while (check16(tin, wantI)) {
#pragma unroll
        for (int it = 0; it < 16; ++it) {
          if (tag_bad(tin[it], wantI)) {
            const int q = it * 256 + tid, row = q >> 7, col = (q & 127) * 8;
            const ull* p = reinterpret_cast<const ull*>(srcI + (size_t)row * HH + col);
            ull lo = __hip_atomic_load(p,     __ATOMIC_RELAXED, __HIP_MEMORY_SCOPE_AGENT);
            ull hi = __hip_atomic_load(p + 1, __ATOMIC_RELAXED, __HIP_MEMORY_SCOPE_AGENT);
            union { ull u[2]; f16x8 v; } c; c.u[0] = lo; c.u[1] = hi;
            tin[it] = c.v;
          }
        }
      }
    }

    // ---------- registers -> LDS ----------
#pragma unroll
    for (int it = 0; it < 16; ++it) {
      const int q = it * 256 + tid, row = q >> 7, col = (q & 127) * 8;
      *reinterpret_cast<f16x8*>(&sIn [(size_t)row * SROW + col]) = tin[it];
      *reinterpret_cast<f16x8*>(&sHid[(size_t)row * SROW + col]) = thid[it];
    }
    __syncthreads();   // barrier A: LDS tiles complete

    // ---------- MFMA from LDS ----------
    f32x4 acc[2][2];
#pragma unroll
    for (int ct = 0; ct < 2; ++ct)
#pragma unroll
      for (int rt = 0; rt < 2; ++rt) acc[ct][rt] = (f32x4){0.f, 0.f, 0.f, 0.f};
#pragma unroll
    for (int j = 0; j < 8; ++j) {
      const int base = w * 256 + kgrp * 8 + j * 32;
      f16x8 ai0 = *reinterpret_cast<const f16x8*>(&sIn [(size_t)crow * SROW + base]);
      f16x8 ai1 = *reinterpret_cast<const f16x8*>(&sIn [(size_t)(16 + crow) * SROW + base]);
      f16x8 ah0 = *reinterpret_cast<const f16x8*>(&sHid[(size_t)crow * SROW + base]);
      f16x8 ah1 = *reinterpret_cast<const f16x8*>(&sHid[(size_t)(16 + crow) * SROW + base]);
#pragma unroll
      for (int ct = 0; ct < 2; ++ct) {
        acc[ct][0] = __builtin_amdgcn_mfma_f32_16x16x32_f16(ai0, wIf[ct][j], acc[ct][0], 0, 0, 0);
        acc[ct][1] = __builtin_amdgcn_mfma_f32_16x16x32_f16(ai1, wIf[ct][j], acc[ct][1], 0, 0, 0);
        acc[ct][0] = __builtin_amdgcn_mfma_f32_16x16x32_f16(ah0, wHf[ct][j], acc[ct][0], 0, 0, 0);
        acc[ct][1] = __builtin_amdgcn_mfma_f32_16x16x32_f16(ah1, wHf[ct][j], acc[ct][1], 0, 0, 0);
      }
    }

    // ---------- cross-wave k-reduce ----------
#pragma unroll
    for (int ct = 0; ct < 2; ++ct)
#pragma unroll
      for (int rt = 0; rt < 2; ++rt)
#pragma unroll
        for (int r = 0; r < 4; ++r)
          RED(w, rt, kgrp * 4 + r, ct * 16 + crow) = acc[ct][rt][r];
    __syncthreads();   // barrier B: RED complete; also fences next sIn writes
                       // (all MFMA LDS reads precede this barrier)

    float v[8];
    if (tid < 128) {
#pragma unroll
      for (int j = 0; j < 8; ++j) {
        float s = bias8[j];
#pragma unroll
        for (int w2 = 0; w2 < 4; ++w2) s += RED(w2, rb2 >> 4, rb2 & 15, c8 + j);
        v[j] = tanhf(s);
      }
      union { _Float16 h[8]; ull u[2]; f16x8 vv; } pk;
#pragma unroll
      for (int j = 0; j < 8; ++j) pk.h[j] = (_Float16)v[j];
      const ull tg = (((t >> rshift) & 1) ^ 1) ? TAGM : 0ULL;
      pk.u[0] = (pk.u[0] & ~TAGM) | tg;
      pk.u[1] = (pk.u[1] & ~TAGM) | tg;
      const size_t off =
          ((size_t)l * (rsmask + 1) + (t & rsmask)) * BB * HH + (size_t)rb2 * HH + c0 + c8;
      // dual store, SAME address: plain (dirty in local L2 -> fast same-XCD
      // settle) + atomic write-through (MALL master -> cross-XCD + termination)
      *reinterpret_cast<f16x8*>(hbuf + off) = pk.vv;
      __hip_atomic_store(reinterpret_cast<ull*>(hbuf + off), pk.u[0],
                         __ATOMIC_RELAXED, __HIP_MEMORY_SCOPE_AGENT);
      __hip_atomic_store(reinterpret_cast<ull*>(hbuf + off) + 1, pk.u[1],
                         __ATOMIC_RELAXED, __HIP_MEMORY_SCOPE_AGENT);

      if (l == NL - 1) {
        f32x4 o0 = {v[0], v[1], v[2], v[3]}, o1 = {v[4], v[5], v[6], v[7]};
        float* po = out + ((size_t)rb2 * LL + t) * HH + c0 + c8;
        __builtin_nontemporal_store(o0, reinterpret_cast<f32x4*>(po));
        __builtin_nontemporal_store(o1, reinterpret_cast<f32x4*>(po + 4));
      }
      if (t == LL - 1) {
        f32x4 o0 = {v[0], v[1], v[2], v[3]}, o1 = {v[4], v[5], v[6], v[7]};
        float* pf = out + (size_t)BB * LL * HH + ((size_t)l * BB + rb2) * HH + c0 + c8;
        __builtin_nontemporal_store(o0, reinterpret_cast<f32x4*>(pf));
        __builtin_nontemporal_store(o1, reinterpret_cast<f32x4*>(pf + 4));
      }
    }

    // ---------- publish (hint) IN-STEP, right after store issue ----------
    // No drain: flag may slightly lead the MALL copy; consumers' tag-settle
    // (atomic tier) absorbs the window. Removes the one-step publish lag.
    if (tid == 0)
      __hip_atomic_store(&pflag[l * TPL + tile], (unsigned)(t + 1), __ATOMIC_RELAXED,
                         __HIP_MEMORY_SCOPE_AGENT);
  }
#undef RED
}

extern "C" void kernel_launch(void* const* d_in, const int* in_sizes, int n_in,
                              void* d_out, int out_size, void* d_ws, size_t ws_size,
                              hipStream_t stream) {
  const float* x  = (const float*)d_in[0];
  const float* h0 = (const float*)d_in[1];
  const float* WI = (const float*)d_in[2];
  const float* BI = (const float*)d_in[3];
  const float* WH = (const float*)d_in[4];
  const float* BH = (const float*)d_in[5];
  float* out = (float*)d_out;

  // RS (slots per layer): prefer 512 = fully write-once h stream (no WAR).
  const size_t perSlot = (size_t)NL * BB * HH * sizeof(_Float16);  // 256 KB
  int rs = 512;
  while (rs > 8 && (size_t)rs * perSlot + 65536 > ws_size) rs >>= 1;
  int rshift = 0;
  while ((1 << rshift) < rs) ++rshift;

  _Float16* hbuf = (_Float16*)d_ws;
  unsigned* pflag = (unsigned*)((char*)d_ws + (size_t)rs * perSlot);

  const int smemBytes = 2 * 32 * SROW * (int)sizeof(_Float16) +
                        4 * 2 * 16 * 34 * (int)sizeof(float);
  static int attrSet = 0;
  if (!attrSet) {
    hipFuncSetAttribute(reinterpret_cast<const void*>(rnn_persist),
                        hipFuncAttributeMaxDynamicSharedMemorySize, smemBytes);
    attrSet = 1;
  }

  hipMemsetAsync(pflag, 0, (size_t)NL * TPL * sizeof(unsigned), stream);
  rnn_persist<<<256, 256, smemBytes, stream>>>(x, h0, WI, BI, WH, BH, out, hbuf,
                                               pflag, rs - 1, rshift);
}

// Round 18
// 3535.011 us; speedup vs baseline: 1.8799x; 1.8799x over previous
//
#include <hip/hip_runtime.h>
#include <hip/hip_fp16.h>

#define BB 32
#define LL 512
#define HH 1024
#define NL 4
#define TPL 16   // tiles (blocks) per layer
#define CPB 64   // cols per block
#define TAGM 0x0001000100010001ULL   // LSB of each f16; per-f16 tags -> tear-proof
#define SROW 1032  // LDS row stride (f16)

typedef unsigned long long ull;
typedef _Float16 f16x8 __attribute__((ext_vector_type(8)));
typedef float    f32x4 __attribute__((ext_vector_type(4)));

__device__ __forceinline__ f16x8 cvt8(const float* __restrict__ p) {
  f32x4 lo = *reinterpret_cast<const f32x4*>(p);
  f32x4 hi = *reinterpret_cast<const f32x4*>(p + 4);
  f16x8 r;
#pragma unroll
  for (int e = 0; e < 4; ++e) { r[e] = (_Float16)lo[e]; r[e + 4] = (_Float16)hi[e]; }
  return r;
}

__device__ __forceinline__ ull tag_bad(f16x8 v, ull want) {
  union { f16x8 v; ull u[2]; } c; c.v = v;
  return ((c.u[0] ^ want) | (c.u[1] ^ want)) & TAGM;
}

// Guaranteed-terminating repair: 8B relaxed agent atomic (MALL) spin.
// Producer dual-stores the same address atomically (round-6-proven).
__device__ __forceinline__ f16x8 fix_q(const _Float16* __restrict__ gsrc, ull want) {
  const ull* p = reinterpret_cast<const ull*>(gsrc);
  union { ull u[2]; f16x8 v; } c;
  do {
    c.u[0] = __hip_atomic_load(p, __ATOMIC_RELAXED, __HIP_MEMORY_SCOPE_AGENT);
  } while ((c.u[0] ^ want) & TAGM);
  do {
    c.u[1] = __hip_atomic_load(p + 1, __ATOMIC_RELAXED, __HIP_MEMORY_SCOPE_AGENT);
  } while ((c.u[1] ^ want) & TAGM);
  return c.v;
}

// Persistent pipeline, 64 active blocks (grid 128): layer = blockIdx&7
// (XCD-locality heuristic only; tags + MALL retry keep correctness
// placement-free). Block: 64 cols, 512 threads, 8 waves (wave = k-eighth),
// weights in VGPRs. Round-15 sync fabric verbatim; 16 blocks/layer halves
// the per-XCD L2 request count (the round-15 floor).
__global__ __launch_bounds__(512, 2) void rnn_persist(
    const float* __restrict__ x,   // [B][L][H] f32
    const float* __restrict__ h0,  // [NL][B][H] f32
    const float* __restrict__ WI,  // [NL][H][H] f32
    const float* __restrict__ BI,  // [NL][H]
    const float* __restrict__ WH,  // [NL][H][H] f32
    const float* __restrict__ BH,  // [NL][H]
    float* __restrict__ out,       // [B][L][H] f32 ++ hfinal [NL][B][H]
    _Float16* __restrict__ hbuf,   // [NL][RS][B][H] f16 (tagged)
    unsigned* __restrict__ pflag,  // [NL][TPL]: v => step v-1 complete
    int rsmask, int rshift) {
  const int l = blockIdx.x & 7;
  if (l >= NL) return;
  const int tile = blockIdx.x >> 3;   // 0..15
  const int c0   = tile * CPB;
  const int tid  = threadIdx.x;       // 0..511
  const int w    = tid >> 6;          // wave 0..7 -> k-eighth [w*128, w*128+128)
  const int lane = tid & 63;
  const int crow = lane & 15;
  const int kgrp = lane >> 4;

  extern __shared__ char smem[];
  _Float16* sIn  = (_Float16*)smem;            // [32][SROW]
  _Float16* sHid = sIn + 32 * SROW;            // [32][SROW]
  float*    redp = (float*)smem;               // [8][32][68] ALIASED over staging
#define RED(W2, R, C) redp[(((W2) * 32 + (R)) * 68) + (C)]

  // ---- weight fragments -> registers (once): both matrices, own k-eighth ----
  f16x8 wIf[4][4], wHf[4][4];
  {
    const float* WIb = WI + (size_t)l * HH * HH;
    const float* WHb = WH + (size_t)l * HH * HH;
#pragma unroll
    for (int ct = 0; ct < 4; ++ct) {
      const size_t row = (size_t)(c0 + ct * 16 + crow) * HH;
#pragma unroll
      for (int j = 0; j < 4; ++j) {
        const int k = w * 128 + kgrp * 8 + j * 32;
        wIf[ct][j] = cvt8(WIb + row + k);
        wHf[ct][j] = cvt8(WHb + row + k);
      }
    }
  }

  // staging: q = it*512+tid -> row=q>>7, col=(q&127)*8 (8 quanta/thread/operand)
  // epilogue: thread -> (row rb, 4 cols at c4) = one 8B tagged quantum
  const int rb = tid >> 4;          // 0..31
  const int c4 = (tid & 15) * 4;    // 0..60
  float bias4[4];
#pragma unroll
  for (int j = 0; j < 4; ++j)
    bias4[j] = BI[l * HH + c0 + c4 + j] + BH[l * HH + c0 + c4 + j];

  for (int t = 0; t < LL; ++t) {
    const ull wantI = (((t >> rshift) & 1) ^ 1) ? TAGM : 0ULL;        // gen t
    const ull wantH = ((((t - 1) >> rshift) & 1) ^ 1) ? TAGM : 0ULL;  // gen t-1

    // ---------- gates (round-15 order, verbatim semantics) ----------
    if (tid < 48) {
      if (tid < 16) {
        if (l > 0)
          while (__hip_atomic_load(&pflag[(l - 1) * TPL + tid], __ATOMIC_RELAXED,
                                   __HIP_MEMORY_SCOPE_AGENT) < (unsigned)(t + 1))
            __builtin_amdgcn_s_sleep(1);
      } else if (tid >= 32) {
        const int Lt = tid - 32;
        if (l < NL - 1 && t > rsmask)
          while (__hip_atomic_load(&pflag[(l + 1) * TPL + Lt], __ATOMIC_RELAXED,
                                   __HIP_MEMORY_SCOPE_AGENT) < (unsigned)(t - rsmask))
            __builtin_amdgcn_s_sleep(1);
      }
    }
    __syncthreads();   // barrier 1: gates passed + drains PREVIOUS step's stores

    // publish step t-1 completion (ordered by barrier-1's implicit drain)
    if (tid == 0 && t > 0)
      __hip_atomic_store(&pflag[l * TPL + tile], (unsigned)t, __ATOMIC_RELAXED,
                         __HIP_MEMORY_SCOPE_AGENT);

    const _Float16* srcI =
        hbuf + ((size_t)(l - 1) * (rsmask + 1) + (t & rsmask)) * BB * HH;
    const _Float16* srcH =
        hbuf + ((size_t)l * (rsmask + 1) + ((t - 1) & rsmask)) * BB * HH;

    // ---------- phase I: input operand -> regs -> settle -> LDS ----------
    {
      f16x8 tq[8];
      if (l == 0) {
#pragma unroll
        for (int it = 0; it < 8; ++it) {
          const int q = it * 512 + tid, row = q >> 7, col = (q & 127) * 8;
          tq[it] = cvt8(x + ((size_t)row * LL + t) * HH + col);
        }
      } else {
#pragma unroll
        for (int it = 0; it < 8; ++it) {
          const int q = it * 512 + tid, row = q >> 7, col = (q & 127) * 8;
          tq[it] = *reinterpret_cast<const f16x8*>(srcI + (size_t)row * HH + col);
        }
        ull badI = 0;
#pragma unroll
        for (int it = 0; it < 8; ++it) badI |= tag_bad(tq[it], wantI);
        if (badI) {
#pragma unroll
          for (int it = 0; it < 8; ++it) {
            const int q = it * 512 + tid, row = q >> 7, col = (q & 127) * 8;
            if (tag_bad(tq[it], wantI))
              tq[it] = fix_q(srcI + (size_t)row * HH + col, wantI);
          }
        }
      }
#pragma unroll
      for (int it = 0; it < 8; ++it) {
        const int q = it * 512 + tid, row = q >> 7, col = (q & 127) * 8;
        *reinterpret_cast<f16x8*>(&sIn[(size_t)row * SROW + col]) = tq[it];
      }
    }

    // ---------- phase H: hidden operand -> regs -> settle -> LDS ----------
    {
      f16x8 tq[8];
      if (t == 0) {
#pragma unroll
        for (int it = 0; it < 8; ++it) {
          const int q = it * 512 + tid, row = q >> 7, col = (q & 127) * 8;
          tq[it] = cvt8(h0 + ((size_t)l * BB + row) * HH + col);
        }
      } else {
#pragma unroll
        for (int it = 0; it < 8; ++it) {
          const int q = it * 512 + tid, row = q >> 7, col = (q & 127) * 8;
          tq[it] = *reinterpret_cast<const f16x8*>(srcH + (size_t)row * HH + col);
        }
        ull badH = 0;
#pragma unroll
        for (int it = 0; it < 8; ++it) badH |= tag_bad(tq[it], wantH);
        if (badH) {   // round-15 settle: volatile tier (same-XCD L2), then MALL
#pragma unroll
          for (int it = 0; it < 8; ++it) {
            const int q = it * 512 + tid, row = q >> 7, col = (q & 127) * 8;
            const _Float16* a = srcH + (size_t)row * HH + col;
            int tries = 0;
            while (tag_bad(tq[it], wantH)) {
              if (tries++ < 64) {
                const volatile ull* vp = reinterpret_cast<const volatile ull*>(a);
                ull lo = vp[0], hi = vp[1];
                union { ull u[2]; f16x8 v; } c; c.u[0] = lo; c.u[1] = hi;
                tq[it] = c.v;
              } else {
                tq[it] = fix_q(a, wantH);
              }
            }
          }
        }
      }
#pragma unroll
      for (int it = 0; it < 8; ++it) {
        const int q = it * 512 + tid, row = q >> 7, col = (q & 127) * 8;
        *reinterpret_cast<f16x8*>(&sHid[(size_t)row * SROW + col]) = tq[it];
      }
    }
    __syncthreads();   // barrier 2: LDS tiles complete

    // ---------- MFMA from LDS (wave = k-eighth, 4 col-subtiles) ----------
    f32x4 acc[4][2];
#pragma unroll
    for (int ct = 0; ct < 4; ++ct)
#pragma unroll
      for (int rt = 0; rt < 2; ++rt) acc[ct][rt] = (f32x4){0.f, 0.f, 0.f, 0.f};
#pragma unroll
    for (int j = 0; j < 4; ++j) {
      const int base = w * 128 + kgrp * 8 + j * 32;
      f16x8 ai0 = *reinterpret_cast<const f16x8*>(&sIn [(size_t)crow * SROW + base]);
      f16x8 ai1 = *reinterpret_cast<const f16x8*>(&sIn [(size_t)(16 + crow) * SROW + base]);
      f16x8 ah0 = *reinterpret_cast<const f16x8*>(&sHid[(size_t)crow * SROW + base]);
      f16x8 ah1 = *reinterpret_cast<const f16x8*>(&sHid[(size_t)(16 + crow) * SROW + base]);
#pragma unroll
      for (int ct = 0; ct < 4; ++ct) {
        acc[ct][0] = __builtin_amdgcn_mfma_f32_16x16x32_f16(ai0, wIf[ct][j], acc[ct][0], 0, 0, 0);
        acc[ct][1] = __builtin_amdgcn_mfma_f32_16x16x32_f16(ai1, wIf[ct][j], acc[ct][1], 0, 0, 0);
        acc[ct][0] = __builtin_amdgcn_mfma_f32_16x16x32_f16(ah0, wHf[ct][j], acc[ct][0], 0, 0, 0);
        acc[ct][1] = __builtin_amdgcn_mfma_f32_16x16x32_f16(ah1, wHf[ct][j], acc[ct][1], 0, 0, 0);
      }
    }
    __syncthreads();   // barrier 3: all LDS reads done (red aliases staging)

    // ---------- cross-wave k-reduce: write partials ----------
#pragma unroll
    for (int ct = 0; ct < 4; ++ct)
#pragma unroll
      for (int rt = 0; rt < 2; ++rt)
#pragma unroll
        for (int r = 0; r < 4; ++r)
          RED(w, rt * 16 + kgrp * 4 + r, ct * 16 + crow) = acc[ct][rt][r];
    __syncthreads();   // barrier 4: partials complete

    // ---------- epilogue: all 512 threads, 4 cols each ----------
    float v[4];
#pragma unroll
    for (int j = 0; j < 4; ++j) {
      float s = bias4[j];
#pragma unroll
      for (int w2 = 0; w2 < 8; ++w2) s += RED(w2, rb, c4 + j);
      v[j] = tanhf(s);
    }
    {
      union { _Float16 h[4]; ull u; } pk;
#pragma unroll
      for (int j = 0; j < 4; ++j) pk.h[j] = (_Float16)v[j];
      const ull tg = (((t >> rshift) & 1) ^ 1) ? TAGM : 0ULL;
      pk.u = (pk.u & ~TAGM) | tg;
      const size_t off =
          ((size_t)l * (rsmask + 1) + (t & rsmask)) * BB * HH + (size_t)rb * HH + c0 + c4;
      // dual store, SAME address (round-15-proven): plain (dirty local L2)
      // + atomic write-through (MALL master / termination guarantee)
      *reinterpret_cast<ull*>(hbuf + off) = pk.u;
      __hip_atomic_store(reinterpret_cast<ull*>(hbuf + off), pk.u,
                         __ATOMIC_RELAXED, __HIP_MEMORY_SCOPE_AGENT);
    }
    if (l == NL - 1) {
      f32x4 o = {v[0], v[1], v[2], v[3]};
      __builtin_nontemporal_store(
          o, reinterpret_cast<f32x4*>(out + ((size_t)rb * LL + t) * HH + c0 + c4));
    }
    if (t == LL - 1) {
      f32x4 o = {v[0], v[1], v[2], v[3]};
      __builtin_nontemporal_store(
          o, reinterpret_cast<f32x4*>(out + (size_t)BB * LL * HH +
                                      ((size_t)l * BB + rb) * HH + c0 + c4));
    }
  }

  // final publish: step LL-1 complete (ordered after drain)
  __syncthreads();
  if (tid == 0)
    __hip_atomic_store(&pflag[l * TPL + tile], (unsigned)LL, __ATOMIC_RELAXED,
                       __HIP_MEMORY_SCOPE_AGENT);
#undef RED
}

extern "C" void kernel_launch(void* const* d_in, const int* in_sizes, int n_in,
                              void* d_out, int out_size, void* d_ws, size_t ws_size,
                              hipStream_t stream) {
  const float* x  = (const float*)d_in[0];
  const float* h0 = (const float*)d_in[1];
  const float* WI = (const float*)d_in[2];
  const float* BI = (const float*)d_in[3];
  const float* WH = (const float*)d_in[4];
  const float* BH = (const float*)d_in[5];
  float* out = (float*)d_out;

  // RS (slots per layer): prefer 512 = fully write-once h stream (no WAR).
  const size_t perSlot = (size_t)NL * BB * HH * sizeof(_Float16);  // 256 KB
  int rs = 512;
  while (rs > 8 && (size_t)rs * perSlot + 65536 > ws_size) rs >>= 1;
  int rshift = 0;
  while ((1 << rshift) < rs) ++rshift;

  _Float16* hbuf = (_Float16*)d_ws;
  unsigned* pflag = (unsigned*)((char*)d_ws + (size_t)rs * perSlot);

  const int smemBytes = 2 * 32 * SROW * (int)sizeof(_Float16);  // 132096 (red aliased)
  static int attrSet = 0;
  if (!attrSet) {
    hipFuncSetAttribute(reinterpret_cast<const void*>(rnn_persist),
                        hipFuncAttributeMaxDynamicSharedMemorySize, smemBytes);
    attrSet = 1;
  }

  hipMemsetAsync(pflag, 0, (size_t)NL * TPL * sizeof(unsigned), stream);
  rnn_persist<<<128, 512, smemBytes, stream>>>(x, h0, WI, BI, WH, BH, out, hbuf,
                                               pflag, rs - 1, rshift);
}